// Round 1
// baseline (69.202 us; speedup 1.0000x reference)
//
#include <hip/hip_runtime.h>
#include <math.h>

// CoverageLoss:
//   N=32 images, Bp=8 boxes/img, F=16 fragments, FP=64 points/fragment.
//   Boundary samples: 100 points = { (0,t),(1,t),(t,0),(t,1) : t = j/24, j=0..24 }.
//   val(n,f,fp) = min_b [ inside_b ? 0 : min_s ||frag - box_point(b,s)||^2 ]
//   out = sum val / (FP * N) = sum / 2048.

#define NIMG 32
#define BPB  8     // boxes per image
#define NF   16
#define NFP  64
#define NSEG 25

__global__ __launch_bounds__(64) void coverage_loss_kernel(
    const float* __restrict__ boxes,    // (NIMG*BPB, 4) xc,yc,w,h
    const float* __restrict__ frags,    // (NIMG, NF, NFP, 2)
    float* __restrict__ out)            // scalar, pre-zeroed
{
    const int blk  = blockIdx.x;        // n*NF + f, 512 blocks
    const int n    = blk >> 4;
    const int lane = threadIdx.x;       // fp index, one wave per block

    const float2 fr = reinterpret_cast<const float2*>(frags)[blk * NFP + lane];
    const float fx = fr.x, fy = fr.y;

    const float inv24 = 1.0f / 24.0f;

    float val = INFINITY;               // min over boxes of (outside * mindist)

    const float* bptr = boxes + n * BPB * 4;   // wave-uniform -> scalar loads
    #pragma unroll
    for (int b = 0; b < BPB; ++b) {
        const float xc = bptr[b * 4 + 0];
        const float yc = bptr[b * 4 + 1];
        const float w  = bptr[b * 4 + 2];
        const float h  = bptr[b * 4 + 3];
        const float lx = xc - 0.5f * w;
        const float ly = yc - 0.5f * h;
        const float hx = xc + 0.5f * w;
        const float hy = yc + 0.5f * h;
        const float ww = hx - lx;       // reference: wh = hi - lo
        const float hh = hy - ly;

        // inside: d1 = frag - lo >= 0  &&  d2 = hi - frag >= 0
        const bool inside = (fx - lx >= 0.0f) && (fy - ly >= 0.0f) &&
                            (hx - fx >= 0.0f) && (hy - fy >= 0.0f);

        // loop-invariant squared offsets to the 4 box sides
        const float dx0 = fx - lx;                 // bx = 0 edge: px = lx
        const float dx1 = fx - (lx + ww);          // bx = 1 edge: px = 1*ww + lx
        const float dy0 = fy - ly;
        const float dy1 = fy - (ly + hh);
        const float dx0s = dx0 * dx0, dx1s = dx1 * dx1;
        const float dy0s = dy0 * dy0, dy1s = dy1 * dy1;

        float m = INFINITY;
        #pragma unroll
        for (int j = 0; j < NSEG; ++j) {
            const float t  = (float)j * inv24;     // linspace(0,1,25)
            const float ex = fx - fmaf(t, ww, lx); // x of (t,0)/(t,1) samples
            const float ey = fy - fmaf(t, hh, ly); // y of (0,t)/(1,t) samples
            const float exs = ex * ex, eys = ey * ey;
            m = fminf(m, dx0s + eys);   // (0, t)
            m = fminf(m, dx1s + eys);   // (1, t)
            m = fminf(m, exs + dy0s);   // (t, 0)
            m = fminf(m, exs + dy1s);   // (t, 1)
        }
        val = fminf(val, inside ? 0.0f : m);
    }

    // wave-64 shuffle reduction
    float s = val;
    #pragma unroll
    for (int off = 32; off > 0; off >>= 1)
        s += __shfl_down(s, off, 64);

    if (lane == 0)
        atomicAdd(out, s * (1.0f / 2048.0f));
}

extern "C" void kernel_launch(void* const* d_in, const int* in_sizes, int n_in,
                              void* d_out, int out_size, void* d_ws, size_t ws_size,
                              hipStream_t stream) {
    const float* boxes = (const float*)d_in[0];   // (256, 4) f32
    const float* frags = (const float*)d_in[1];   // (32,16,64,2) f32
    // d_in[2] = obj_to_img (unused by the reference computation)
    float* out = (float*)d_out;

    hipMemsetAsync(out, 0, sizeof(float) * out_size, stream);
    coverage_loss_kernel<<<NIMG * NF, 64, 0, stream>>>(boxes, frags, out);
}

// Round 2
// 61.938 us; speedup vs baseline: 1.1173x; 1.1173x over previous
//
#include <hip/hip_runtime.h>
#include <math.h>

// CoverageLoss:
//   N=32 images, Bp=8 boxes/img, F=16 fragments, FP=64 points/fragment.
//   Boundary samples: 100 points = { (0,t),(1,t),(t,0),(t,1) : t = j/24, j=0..24 }.
//   val(n,f,fp) = min_b [ inside_b ? 0 : min_s ||frag - box_point(b,s)||^2 ]
//   out = sum val / (FP * N) = sum / 2048.
//
// Two dispatches, no atomics, no memset:
//   k1: 512 blocks (1 wave each) -> partial sums in d_ws (pure overwrite)
//   k2: 1 wave reduces 512 partials -> d_out[0]

#define NIMG 32
#define BPB  8     // boxes per image
#define NF   16
#define NFP  64
#define NSEG 25
#define NBLK (NIMG * NF)   // 512

__global__ __launch_bounds__(64) void coverage_partial_kernel(
    const float* __restrict__ boxes,    // (NIMG*BPB, 4) xc,yc,w,h
    const float* __restrict__ frags,    // (NIMG, NF, NFP, 2)
    float* __restrict__ partials)       // (NBLK,) in d_ws, overwritten
{
    const int blk  = blockIdx.x;        // n*NF + f
    const int n    = blk >> 4;
    const int lane = threadIdx.x;       // fp index, one wave per block

    const float2 fr = reinterpret_cast<const float2*>(frags)[blk * NFP + lane];
    const float fx = fr.x, fy = fr.y;

    const float inv24 = 1.0f / 24.0f;

    float val = INFINITY;               // min over boxes of (outside * mindist)

    const float* bptr = boxes + n * BPB * 4;   // wave-uniform -> scalar loads
    #pragma unroll
    for (int b = 0; b < BPB; ++b) {
        const float xc = bptr[b * 4 + 0];
        const float yc = bptr[b * 4 + 1];
        const float w  = bptr[b * 4 + 2];
        const float h  = bptr[b * 4 + 3];
        const float lx = xc - 0.5f * w;
        const float ly = yc - 0.5f * h;
        const float hx = xc + 0.5f * w;
        const float hy = yc + 0.5f * h;
        const float ww = hx - lx;       // reference: wh = hi - lo
        const float hh = hy - ly;

        // inside: d1 = frag - lo >= 0  &&  d2 = hi - frag >= 0
        const bool inside = (fx - lx >= 0.0f) && (fy - ly >= 0.0f) &&
                            (hx - fx >= 0.0f) && (hy - fy >= 0.0f);

        // loop-invariant squared offsets to the 4 box sides
        const float dx0 = fx - lx;                 // bx = 0 edge: px = lx
        const float dx1 = fx - (lx + ww);          // bx = 1 edge: px = lx + 1*ww
        const float dy0 = fy - ly;
        const float dy1 = fy - (ly + hh);
        const float dx0s = dx0 * dx0, dx1s = dx1 * dx1;
        const float dy0s = dy0 * dy0, dy1s = dy1 * dy1;

        float m = INFINITY;
        #pragma unroll
        for (int j = 0; j < NSEG; ++j) {
            const float t  = (float)j * inv24;     // linspace(0,1,25)
            const float ex = fx - fmaf(t, ww, lx); // x of (t,0)/(t,1) samples
            const float ey = fy - fmaf(t, hh, ly); // y of (0,t)/(1,t) samples
            const float exs = ex * ex, eys = ey * ey;
            m = fminf(m, dx0s + eys);   // (0, t)
            m = fminf(m, dx1s + eys);   // (1, t)
            m = fminf(m, exs + dy0s);   // (t, 0)
            m = fminf(m, exs + dy1s);   // (t, 1)
        }
        val = fminf(val, inside ? 0.0f : m);
    }

    // wave-64 shuffle reduction
    float s = val;
    #pragma unroll
    for (int off = 32; off > 0; off >>= 1)
        s += __shfl_down(s, off, 64);

    if (lane == 0)
        partials[blk] = s;
}

__global__ __launch_bounds__(64) void coverage_reduce_kernel(
    const float* __restrict__ partials,  // (NBLK,)
    float* __restrict__ out)             // scalar, overwritten
{
    const int lane = threadIdx.x;
    float s = 0.0f;
    #pragma unroll
    for (int k = 0; k < NBLK / 64; ++k)
        s += partials[lane + 64 * k];
    #pragma unroll
    for (int off = 32; off > 0; off >>= 1)
        s += __shfl_down(s, off, 64);
    if (lane == 0)
        out[0] = s * (1.0f / 2048.0f);
}

extern "C" void kernel_launch(void* const* d_in, const int* in_sizes, int n_in,
                              void* d_out, int out_size, void* d_ws, size_t ws_size,
                              hipStream_t stream) {
    const float* boxes = (const float*)d_in[0];   // (256, 4) f32
    const float* frags = (const float*)d_in[1];   // (32,16,64,2) f32
    // d_in[2] = obj_to_img (unused by the reference computation)
    float* partials = (float*)d_ws;
    float* out = (float*)d_out;

    coverage_partial_kernel<<<NBLK, 64, 0, stream>>>(boxes, frags, partials);
    coverage_reduce_kernel<<<1, 64, 0, stream>>>(partials, out);
}